// Round 7
// baseline (215.532 us; speedup 1.0000x reference)
//
#include <hip/hip_runtime.h>
#include <hip/hip_bf16.h>

#define T_ 8
#define N0_ 32
#define N1_ 32
#define SP_ (N0_*N1_)   /* 1024 spatial cells */
#define S_ (T_*SP_)     /* 8192 space-time cells */
#define E_ 256
#define P_ 16
#define NH_ 8
#define HD_ 32

typedef __attribute__((ext_vector_type(8))) short short8;
typedef __attribute__((ext_vector_type(4))) float f32x4;
typedef __attribute__((ext_vector_type(8))) unsigned short u16x8;

__device__ __forceinline__ unsigned short f2bf(float f) {
  __hip_bfloat16 h = __float2bfloat16(f);
  return *reinterpret_cast<unsigned short*>(&h);
}
__device__ __forceinline__ float bf2f(unsigned short u) {
  return __uint_as_float((unsigned)u << 16);
}

// ---------------- stats: xmin & spacing per batch (matches reference fp32 ops) ------------
__global__ void stats_kernel(const float* __restrict__ tg, const float* __restrict__ grid,
                             float* __restrict__ stats, int m) {
  int lane = threadIdx.x;  // 64 threads, 1 block
  float mn0 = 1e30f, mx0 = -1e30f, mn1 = 1e30f, mx1 = -1e30f;
  for (int i = lane; i < SP_; i += 64) {
    float g0 = grid[i*2], g1 = grid[i*2+1];
    mn0 = fminf(mn0, g0); mx0 = fmaxf(mx0, g0);
    mn1 = fminf(mn1, g1); mx1 = fmaxf(mx1, g1);
  }
  for (int msk = 32; msk; msk >>= 1) {
    mn0 = fminf(mn0, __shfl_xor(mn0, msk));
    mx0 = fmaxf(mx0, __shfl_xor(mx0, msk));
    mn1 = fminf(mn1, __shfl_xor(mn1, msk));
    mx1 = fmaxf(mx1, __shfl_xor(mx1, msk));
  }
  if (lane == 0) {
    for (int b = 0; b < m; ++b) {
      float tmn = 1e30f, tmx = -1e30f;
      for (int t = 0; t < T_; ++t) {
        float v = tg[b*T_ + t];
        tmn = fminf(tmn, v); tmx = fmaxf(tmx, v);
      }
      float* st = stats + b*8;
      st[0] = tmn; st[1] = mn0; st[2] = mn1;
      st[3] = (tmx - tmn) / (float)(T_ - 1);
      st[4] = (mx0 - mn0) / (float)(N0_ - 1);
      st[5] = (mx1 - mn1) / (float)(N1_ - 1);
    }
  }
}

// ---------------- x_grid output ------------------------------------------------------------
__global__ void xgrid_kernel(const float* __restrict__ tg, const float* __restrict__ grid,
                             float* __restrict__ out, int total) {
  int idx = blockIdx.x * blockDim.x + threadIdx.x;  // over m*T*1024
  if (idx >= total) return;
  int sp = idx & (SP_ - 1);
  int bt = idx >> 10;
  out[idx*3 + 0] = tg[bt];
  out[idx*3 + 1] = grid[sp*2 + 0];
  out[idx*3 + 2] = grid[sp*2 + 1];
}

// ---------------- point -> cell assignment (fp32 op order == reference) --------------------
__global__ void assign_kernel(const float* __restrict__ x, const float* __restrict__ stats,
                              int* __restrict__ counts, int* __restrict__ cell_raw,
                              int m, int n) {
  int i = blockIdx.x * blockDim.x + threadIdx.x;
  if (i >= m*n) return;
  int b = i / n;
  int j = i - b*n;
  const float* st = stats + b*8;
  float xt = x[(size_t)i*3 + 0], x0 = x[(size_t)i*3 + 1], x1 = x[(size_t)i*3 + 2];
  float m0 = floorf((xt - st[0] + st[3]*0.5f) / st[3]);
  float m1 = floorf((x0 - st[1] + st[4]*0.5f) / st[4]);
  float m2 = floorf((x1 - st[2] + st[5]*0.5f) / st[5]);
  m0 = fminf(fmaxf(m0, 0.f), (float)(T_ - 1));
  m1 = fminf(fmaxf(m1, 0.f), (float)(N0_ - 1));
  m2 = fminf(fmaxf(m2, 0.f), (float)(N1_ - 1));
  int s = (int)m0 * SP_ + (int)m1 * N1_ + (int)m2;
  int cg = b * S_ + s;
  int old = atomicAdd(&counts[cg], 1);
  if (old < P_) cell_raw[(size_t)cg * P_ + old] = j;
}

// ------- per-cell: sort indices (determinism + exact first-15 drop), pack eff+pts ---------
__global__ void finalize_kernel(const int* __restrict__ counts, int* __restrict__ cell_raw,
                                int* __restrict__ pts2, int total) {
  int cg = blockIdx.x * blockDim.x + threadIdx.x;
  if (cg >= total) return;
  int cnt = counts[cg];
  int stored = cnt < P_ ? cnt : P_;
  int eff = cnt < (P_ - 1) ? cnt : (P_ - 1);
  int* p = cell_raw + (size_t)cg * P_;
  for (int i = 1; i < stored; ++i) {   // insertion sort ascending (original index order)
    int key = p[i]; int j = i - 1;
    while (j >= 0 && p[j] > key) { p[j+1] = p[j]; --j; }
    p[j+1] = key;
  }
  int* o = pts2 + (size_t)cg * P_;
  o[0] = eff;
  for (int i = 0; i < eff; ++i) o[1 + i] = p[i];
}

// ---------------- weight transpose+convert: wT[1024][256] bf16 = [Wq|Wk|Wv|Wo]^T ----------
__global__ __launch_bounds__(256) void wtrans_kernel(const float* __restrict__ Wq,
                                                     const float* __restrict__ Wk,
                                                     const float* __restrict__ Wv,
                                                     const float* __restrict__ Wo,
                                                     unsigned short* __restrict__ wT) {
  int mat = blockIdx.x >> 4;
  int tile = blockIdx.x & 15;
  int tr = (tile >> 2) * 64;   // row (k) offset in W
  int tc = (tile & 3) * 64;    // col offset in W
  const float* W = mat == 0 ? Wq : mat == 1 ? Wk : mat == 2 ? Wv : Wo;
  __shared__ float ts[64][65];
  int t = threadIdx.x;
  int r = t >> 2, c0 = (t & 3) * 16;
#pragma unroll
  for (int i = 0; i < 4; ++i) {
    float4 v = *(const float4*)&W[(size_t)(tr + r) * 256 + tc + c0 + i*4];
    ts[r][c0 + i*4 + 0] = v.x; ts[r][c0 + i*4 + 1] = v.y;
    ts[r][c0 + i*4 + 2] = v.z; ts[r][c0 + i*4 + 3] = v.w;
  }
  __syncthreads();
  u16x8 o0, o1;
#pragma unroll
  for (int i = 0; i < 8; ++i) o0[i] = f2bf(ts[c0 + i][r]);
#pragma unroll
  for (int i = 0; i < 8; ++i) o1[i] = f2bf(ts[c0 + 8 + i][r]);
  unsigned short* dst = wT + (size_t)(mat * 256 + tc + r) * 256 + tr + c0;
  *(u16x8*)dst = o0;
  *(u16x8*)(dst + 8) = o1;
}

// ============ B-in-register zero-barrier streaming GEMM ====================================
// C[M,N] = A[M,256] @ BT[N,256]^T.  Each wave owns a 32-col panel of B for the FULL K=256
// in registers (16 short8 frags = 64 VGPR, loaded once, L2-hot), then grid-strides over
// 32-row A chunks: A global->reg frags (2-deep double-buffer prefetch, compile-time
// named bufs), 4 MFMA per kf.  No LDS, no barriers, fully independent waves.
template <typename InT, typename OutT>
__global__ __launch_bounds__(256, 3) void gemm_breg(const InT* __restrict__ A,
                                                    const unsigned short* __restrict__ BT,
                                                    OutT* __restrict__ C,
                                                    int M, int CP, int ldc) {
  int wid = threadIdx.x >> 6;
  int lane = threadIdx.x & 63;
  int gw = blockIdx.x * 4 + wid;
  int cp = gw % CP;
  int rw = gw / CP;
  int RC = (gridDim.x * 4) / CP;
  int l15 = lane & 15;
  int slot = lane >> 4;

  // ---- B fragments: cols cp*32 + {l15, 16+l15}, full K ----
  short8 bfr0[8], bfr1[8];
  {
    const unsigned short* bp = BT + (size_t)(cp * 32 + l15) * 256 + slot * 8;
#pragma unroll
    for (int kf = 0; kf < 8; ++kf) {
      bfr0[kf] = *reinterpret_cast<const short8*>(bp + kf * 32);
      bfr1[kf] = *reinterpret_cast<const short8*>(bp + 16 * 256 + kf * 32);
    }
  }

  int nchunk = M >> 5;
  int ccol = cp * 32 + l15;

  for (int ch = rw; ch < nchunk; ch += RC) {
    const InT* a0 = A + (size_t)(ch * 32 + l15) * 256 + slot * 8;
    const InT* a1 = a0 + 16 * 256;
    f32x4 acc00 = {}, acc01 = {}, acc10 = {}, acc11 = {};

    float4 pf0_0a, pf0_0b, pf0_1a, pf0_1b;   // buf0 (fp32 path)
    float4 pf1_0a, pf1_0b, pf1_1a, pf1_1b;   // buf1
    u16x8 ph0_0, ph0_1, ph1_0, ph1_1;        // bf16 path bufs
    int koff = 0;

#define LOADA_(B) do { \
    if constexpr (__is_same(InT, float)) { \
      pf##B##_0a = *(const float4*)(a0 + koff); pf##B##_0b = *(const float4*)(a0 + koff + 4); \
      pf##B##_1a = *(const float4*)(a1 + koff); pf##B##_1b = *(const float4*)(a1 + koff + 4); \
    } else { \
      ph##B##_0 = *(const u16x8*)((const unsigned short*)a0 + koff); \
      ph##B##_1 = *(const u16x8*)((const unsigned short*)a1 + koff); \
    } \
    koff += 32; } while (0)

#define USEA_(B, KF) do { \
    short8 af0, af1; \
    if constexpr (__is_same(InT, float)) { \
      af0[0]=f2bf(pf##B##_0a.x); af0[1]=f2bf(pf##B##_0a.y); af0[2]=f2bf(pf##B##_0a.z); af0[3]=f2bf(pf##B##_0a.w); \
      af0[4]=f2bf(pf##B##_0b.x); af0[5]=f2bf(pf##B##_0b.y); af0[6]=f2bf(pf##B##_0b.z); af0[7]=f2bf(pf##B##_0b.w); \
      af1[0]=f2bf(pf##B##_1a.x); af1[1]=f2bf(pf##B##_1a.y); af1[2]=f2bf(pf##B##_1a.z); af1[3]=f2bf(pf##B##_1a.w); \
      af1[4]=f2bf(pf##B##_1b.x); af1[5]=f2bf(pf##B##_1b.y); af1[6]=f2bf(pf##B##_1b.z); af1[7]=f2bf(pf##B##_1b.w); \
    } else { \
      af0 = *reinterpret_cast<short8*>(&ph##B##_0); \
      af1 = *reinterpret_cast<short8*>(&ph##B##_1); \
    } \
    acc00 = __builtin_amdgcn_mfma_f32_16x16x32_bf16(af0, bfr0[KF], acc00, 0, 0, 0); \
    acc01 = __builtin_amdgcn_mfma_f32_16x16x32_bf16(af0, bfr1[KF], acc01, 0, 0, 0); \
    acc10 = __builtin_amdgcn_mfma_f32_16x16x32_bf16(af1, bfr0[KF], acc10, 0, 0, 0); \
    acc11 = __builtin_amdgcn_mfma_f32_16x16x32_bf16(af1, bfr1[KF], acc11, 0, 0, 0); } while (0)

    LOADA_(0); LOADA_(1);
    USEA_(0, 0); LOADA_(0);
    USEA_(1, 1); LOADA_(1);
    USEA_(0, 2); LOADA_(0);
    USEA_(1, 3); LOADA_(1);
    USEA_(0, 4); LOADA_(0);
    USEA_(1, 5); LOADA_(1);
    USEA_(0, 6);
    USEA_(1, 7);

#undef LOADA_
#undef USEA_

    // ---- epilogue: C/D layout col=lane&15, row=(lane>>4)*4+j ----
    int rb = ch * 32 + slot * 4;
#pragma unroll
    for (int j = 0; j < 4; ++j) {
      size_t r0o = (size_t)(rb + j) * ldc + ccol;
      size_t r1o = (size_t)(rb + 16 + j) * ldc + ccol;
      if constexpr (__is_same(OutT, float)) {
        C[r0o]      = acc00[j];
        C[r0o + 16] = acc01[j];
        C[r1o]      = acc10[j];
        C[r1o + 16] = acc11[j];
      } else {
        C[r0o]      = __float2bfloat16(acc00[j]);
        C[r0o + 16] = __float2bfloat16(acc01[j]);
        C[r1o]      = __float2bfloat16(acc10[j]);
        C[r1o + 16] = __float2bfloat16(acc11[j]);
      }
    }
  }
}

// ---------------- masked cross-attention: one wave per cell, online softmax ---------------
__global__ __launch_bounds__(256) void attn_kernel(
    const float* __restrict__ lat,          // [1024][768]  q|k|v
    const __hip_bfloat16* __restrict__ kv,  // [m*n][512]   k|v
    const int* __restrict__ pts2,           // [MS][16]: w0=eff, w1..15 sorted pt indices
    __hip_bfloat16* __restrict__ attn_out, int n) {
  const float scale = 0.17677669529663687f;  // 1/sqrt(32)
  int wid = threadIdx.x >> 6;
  int lane = threadIdx.x & 63;
  int cellg = blockIdx.x * 4 + wid;
  int b = cellg >> 13;                 // S_=8192, cells per batch
  int c = cellg & (SP_ - 1);           // spatial index -> latent row
  int d0 = lane << 2;                  // 4 dims per lane

  const int* pp = pts2 + (size_t)cellg * P_;
  int4 h0 = *(const int4*)pp;          // eff, pt0, pt1, pt2 (broadcast load)
  int eff = h0.x;

  const float* latc = lat + c * 768 + d0;
  float4 q  = *(const float4*)latc;
  float4 kl = *(const float4*)(latc + 256);
  float4 vl = *(const float4*)(latc + 512);

  // grid-token logit -> init online-softmax state
  float part = q.x*kl.x + q.y*kl.y + q.z*kl.z + q.w*kl.w;
  part += __shfl_xor(part, 1);
  part += __shfl_xor(part, 2);
  part += __shfl_xor(part, 4);         // head-local (8 lanes = 32 dims)
  float mx = part * scale;
  float ssum = 1.f;
  float4 acc = vl;

  const unsigned short* kvp = (const unsigned short*)kv;
  size_t bbase = (size_t)b * n;

  int pt[4]; pt[0] = h0.y; pt[1] = h0.z; pt[2] = h0.w; pt[3] = 0;
  int done = 0, cap = 3;
  while (done < eff) {
    int np = eff - done; if (np > cap) np = cap;
    ushort4 kr[4], vr[4];
#pragma unroll
    for (int i = 0; i < 4; ++i) if (i < np) {
      size_t row = (bbase + (size_t)pt[i]) * 512;
      kr[i] = *(const ushort4*)(kvp + row + d0);
      vr[i] = *(const ushort4*)(kvp + row + 256 + d0);
    }
#pragma unroll
    for (int i = 0; i < 4; ++i) if (i < np) {
      float p = q.x*bf2f(kr[i].x) + q.y*bf2f(kr[i].y) + q.z*bf2f(kr[i].z) + q.w*bf2f(kr[i].w);
      p += __shfl_xor(p, 1);
      p += __shfl_xor(p, 2);
      p += __shfl_xor(p, 4);
      p *= scale;
      float m2 = fmaxf(mx, p);
      float corr = __expf(mx - m2);
      float e = __expf(p - m2);
      ssum = ssum * corr + e;
      acc.x = acc.x * corr + e * bf2f(vr[i].x);
      acc.y = acc.y * corr + e * bf2f(vr[i].y);
      acc.z = acc.z * corr + e * bf2f(vr[i].z);
      acc.w = acc.w * corr + e * bf2f(vr[i].w);
      mx = m2;
    }
    done += np;
    cap = 4;
    if (done < eff) {
      int4 h = *(const int4*)(pp + 1 + done);   // done in {3,7,11} -> aligned
      pt[0] = h.x; pt[1] = h.y; pt[2] = h.z; pt[3] = h.w;
    }
  }
  float inv = 1.f / ssum;
  ushort4 o;
  o.x = f2bf(acc.x * inv); o.y = f2bf(acc.y * inv);
  o.z = f2bf(acc.z * inv); o.w = f2bf(acc.w * inv);
  *(ushort4*)((unsigned short*)attn_out + (size_t)cellg * E_ + d0) = o;
}

// -------------------------------------------------------------------------------------------
extern "C" void kernel_launch(void* const* d_in, const int* in_sizes, int n_in,
                              void* d_out, int out_size, void* d_ws, size_t ws_size,
                              hipStream_t stream) {
  const float* x       = (const float*)d_in[0];
  const float* z       = (const float*)d_in[1];
  const float* tg      = (const float*)d_in[2];
  const float* latents = (const float*)d_in[3];
  const float* grid    = (const float*)d_in[4];
  const float* Wq      = (const float*)d_in[5];
  const float* Wk      = (const float*)d_in[6];
  const float* Wv      = (const float*)d_in[7];
  const float* Wo      = (const float*)d_in[8];

  int m = in_sizes[2] / T_;              // 4
  int n = in_sizes[1] / (m * E_);        // 16384
  int MS = m * S_;                       // 32768
  float* out = (float*)d_out;

  // ---- workspace carve (256B aligned) ----
  char* w = (char*)d_ws;
  auto alloc = [&](size_t bytes) { char* p = w; w += (bytes + 255) & ~(size_t)255; return p; };
  float* stats      = (float*)alloc((size_t)m * 8 * 4);
  int*   counts     = (int*)  alloc((size_t)MS * 4);
  int*   cell_raw   = (int*)  alloc((size_t)MS * P_ * 4);
  int*   pts2       = (int*)  alloc((size_t)MS * P_ * 4);
  unsigned short* wT = (unsigned short*)alloc((size_t)1024 * 256 * 2);
  float* lat        = (float*)alloc((size_t)SP_ * 768 * 4);
  __hip_bfloat16* kv       = (__hip_bfloat16*)alloc((size_t)m * n * 512 * 2);
  __hip_bfloat16* attn_out = (__hip_bfloat16*)alloc((size_t)MS * E_ * 2);

  hipMemsetAsync(counts, 0, (size_t)MS * 4, stream);
  stats_kernel<<<1, 64, 0, stream>>>(tg, grid, stats, m);

  int tot_xg = m * T_ * SP_;             // 32768 grid sites
  xgrid_kernel<<<(tot_xg + 255)/256, 256, 0, stream>>>(tg, grid, out, tot_xg);

  assign_kernel<<<(m*n + 255)/256, 256, 0, stream>>>(x, stats, counts, cell_raw, m, n);
  finalize_kernel<<<(MS + 255)/256, 256, 0, stream>>>(counts, cell_raw, pts2, MS);

  // weights: transpose + convert to bf16  [Wq|Wk|Wv|Wo]^T
  wtrans_kernel<<<64, 256, 0, stream>>>(Wq, Wk, Wv, Wo, wT);

  // latent projections fused: lat[1024,768] = latents @ [Wq|Wk|Wv]
  // CP=24 col-panels, 192 blocks = 768 waves, 1 chunk/wave
  gemm_breg<float, float><<<192, 256, 0, stream>>>(latents, wT, lat, SP_, 24, 768);

  // point projections fused: kv[m*n,512] = z @ [Wk|Wv]
  // CP=16, 1024 blocks = 4096 waves, 8 chunks/wave
  gemm_breg<float, __hip_bfloat16><<<1024, 256, 0, stream>>>(
      z, wT + (size_t)256*256, (__hip_bfloat16*)kv, m*n, 16, 512);

  // attention: one wave per cell
  attn_kernel<<<MS/4, 256, 0, stream>>>(lat, kv, pts2, attn_out, n);

  // output projection -> z_grid: CP=8, 512 blocks = 2048 waves, 4 chunks/wave
  gemm_breg<__hip_bfloat16, float><<<512, 256, 0, stream>>>(
      attn_out, wT + (size_t)768*256, out + (size_t)tot_xg * 3, MS, 8, 256);
}

// Round 8
// 110.239 us; speedup vs baseline: 1.9551x; 1.9551x over previous
//
#include <hip/hip_runtime.h>
#include <hip/hip_bf16.h>

#define T_ 8
#define N0_ 32
#define N1_ 32
#define SP_ (N0_*N1_)   /* 1024 spatial cells */
#define S_ (T_*SP_)     /* 8192 space-time cells */
#define E_ 256
#define P_ 16
#define NH_ 8
#define HD_ 32

typedef __attribute__((ext_vector_type(8))) short short8;
typedef __attribute__((ext_vector_type(4))) float f32x4;
typedef __attribute__((ext_vector_type(8))) unsigned short u16x8;

__device__ __forceinline__ unsigned short f2bf(float f) {
  __hip_bfloat16 h = __float2bfloat16(f);
  return *reinterpret_cast<unsigned short*>(&h);
}
__device__ __forceinline__ float bf2f(unsigned short u) {
  return __uint_as_float((unsigned)u << 16);
}

// ---------------- stats: xmin & spacing per batch (matches reference fp32 ops) ------------
__global__ void stats_kernel(const float* __restrict__ tg, const float* __restrict__ grid,
                             float* __restrict__ stats, int m) {
  int lane = threadIdx.x;  // 64 threads, 1 block
  float mn0 = 1e30f, mx0 = -1e30f, mn1 = 1e30f, mx1 = -1e30f;
  for (int i = lane; i < SP_; i += 64) {
    float g0 = grid[i*2], g1 = grid[i*2+1];
    mn0 = fminf(mn0, g0); mx0 = fmaxf(mx0, g0);
    mn1 = fminf(mn1, g1); mx1 = fmaxf(mx1, g1);
  }
  for (int msk = 32; msk; msk >>= 1) {
    mn0 = fminf(mn0, __shfl_xor(mn0, msk));
    mx0 = fmaxf(mx0, __shfl_xor(mx0, msk));
    mn1 = fminf(mn1, __shfl_xor(mn1, msk));
    mx1 = fmaxf(mx1, __shfl_xor(mx1, msk));
  }
  if (lane == 0) {
    for (int b = 0; b < m; ++b) {
      float tmn = 1e30f, tmx = -1e30f;
      for (int t = 0; t < T_; ++t) {
        float v = tg[b*T_ + t];
        tmn = fminf(tmn, v); tmx = fmaxf(tmx, v);
      }
      float* st = stats + b*8;
      st[0] = tmn; st[1] = mn0; st[2] = mn1;
      st[3] = (tmx - tmn) / (float)(T_ - 1);
      st[4] = (mx0 - mn0) / (float)(N0_ - 1);
      st[5] = (mx1 - mn1) / (float)(N1_ - 1);
    }
  }
}

// ---------------- x_grid output ------------------------------------------------------------
__global__ void xgrid_kernel(const float* __restrict__ tg, const float* __restrict__ grid,
                             float* __restrict__ out, int total) {
  int idx = blockIdx.x * blockDim.x + threadIdx.x;  // over m*T*1024
  if (idx >= total) return;
  int sp = idx & (SP_ - 1);
  int bt = idx >> 10;
  out[idx*3 + 0] = tg[bt];
  out[idx*3 + 1] = grid[sp*2 + 0];
  out[idx*3 + 2] = grid[sp*2 + 1];
}

// ---------------- point -> cell assignment (fp32 op order == reference) --------------------
__global__ void assign_kernel(const float* __restrict__ x, const float* __restrict__ stats,
                              int* __restrict__ counts, int* __restrict__ cell_raw,
                              int m, int n) {
  int i = blockIdx.x * blockDim.x + threadIdx.x;
  if (i >= m*n) return;
  int b = i / n;
  int j = i - b*n;
  const float* st = stats + b*8;
  float xt = x[(size_t)i*3 + 0], x0 = x[(size_t)i*3 + 1], x1 = x[(size_t)i*3 + 2];
  float m0 = floorf((xt - st[0] + st[3]*0.5f) / st[3]);
  float m1 = floorf((x0 - st[1] + st[4]*0.5f) / st[4]);
  float m2 = floorf((x1 - st[2] + st[5]*0.5f) / st[5]);
  m0 = fminf(fmaxf(m0, 0.f), (float)(T_ - 1));
  m1 = fminf(fmaxf(m1, 0.f), (float)(N0_ - 1));
  m2 = fminf(fmaxf(m2, 0.f), (float)(N1_ - 1));
  int s = (int)m0 * SP_ + (int)m1 * N1_ + (int)m2;
  int cg = b * S_ + s;
  int old = atomicAdd(&counts[cg], 1);
  if (old < P_) cell_raw[(size_t)cg * P_ + old] = j;
}

// ------- per-cell: sort indices (determinism + exact first-15 drop), pack eff+pts ---------
__global__ void finalize_kernel(const int* __restrict__ counts, int* __restrict__ cell_raw,
                                int* __restrict__ pts2, int total) {
  int cg = blockIdx.x * blockDim.x + threadIdx.x;
  if (cg >= total) return;
  int cnt = counts[cg];
  int stored = cnt < P_ ? cnt : P_;
  int eff = cnt < (P_ - 1) ? cnt : (P_ - 1);
  int* p = cell_raw + (size_t)cg * P_;
  for (int i = 1; i < stored; ++i) {   // insertion sort ascending (original index order)
    int key = p[i]; int j = i - 1;
    while (j >= 0 && p[j] > key) { p[j+1] = p[j]; --j; }
    p[j+1] = key;
  }
  int* o = pts2 + (size_t)cg * P_;
  o[0] = eff;
  for (int i = 0; i < eff; ++i) o[1 + i] = p[i];
}

// ---------------- weight transpose+convert: wT[1024][256] bf16 = [Wq|Wk|Wv|Wo]^T ----------
__global__ __launch_bounds__(256) void wtrans_kernel(const float* __restrict__ Wq,
                                                     const float* __restrict__ Wk,
                                                     const float* __restrict__ Wv,
                                                     const float* __restrict__ Wo,
                                                     unsigned short* __restrict__ wT) {
  int mat = blockIdx.x >> 4;
  int tile = blockIdx.x & 15;
  int tr = (tile >> 2) * 64;   // row (k) offset in W
  int tc = (tile & 3) * 64;    // col offset in W
  const float* W = mat == 0 ? Wq : mat == 1 ? Wk : mat == 2 ? Wv : Wo;
  __shared__ float ts[64][65];
  int t = threadIdx.x;
  int r = t >> 2, c0 = (t & 3) * 16;
#pragma unroll
  for (int i = 0; i < 4; ++i) {
    float4 v = *(const float4*)&W[(size_t)(tr + r) * 256 + tc + c0 + i*4];
    ts[r][c0 + i*4 + 0] = v.x; ts[r][c0 + i*4 + 1] = v.y;
    ts[r][c0 + i*4 + 2] = v.z; ts[r][c0 + i*4 + 3] = v.w;
  }
  __syncthreads();
  u16x8 o0, o1;
#pragma unroll
  for (int i = 0; i < 8; ++i) o0[i] = f2bf(ts[c0 + i][r]);
#pragma unroll
  for (int i = 0; i < 8; ++i) o1[i] = f2bf(ts[c0 + 8 + i][r]);
  unsigned short* dst = wT + (size_t)(mat * 256 + tc + r) * 256 + tr + c0;
  *(u16x8*)dst = o0;
  *(u16x8*)(dst + 8) = o1;
}

// ============ pipelined LDS-tile GEMM: C[M,N] = A[M,256] @ BT[N,256]^T =====================
// 512 thr / 8 waves, tile 128x128, BK=64 (4 K-steps). XOR-swizzled LDS (conflict-free).
// Raw s_barrier + lgkmcnt(0) only (NO vmcnt drain): next K-tile's global loads are issued
// before the barrier and stay in flight across the whole compute phase (T14 + counted-wait).
template <typename InT, typename OutT>
__global__ __launch_bounds__(512, 4) void gemm_ktile(const InT* __restrict__ A,
                                                     const unsigned short* __restrict__ BT,
                                                     OutT* __restrict__ C,
                                                     int M, int CP, int ldc) {
  __shared__ unsigned short As[128 * 64];  // elem (row,k): off = row*64 + ((k8 ^ (row&7))*8 + (k&7))
  __shared__ unsigned short Bs[128 * 64];
  int tid = threadIdx.x;
  int nb = gridDim.x, bid = blockIdx.x;
  int L = bid;
  if ((nb & 7) == 0) L = (bid & 7) * (nb >> 3) + (bid >> 3);   // XCD-chunked swizzle
  int rp = L / CP, cp = L - rp * CP;

  // staging mapping: thread -> (row/col srow, k-quarter kq), 16 elements each
  int srow = tid >> 2;              // 0..127
  int kq   = tid & 3;               // k quarter (16 elems)
  int kq2  = kq * 2;                // first k8-group
  unsigned sw = srow & 7;

  const float* aF = nullptr;
  const unsigned short* aH = nullptr;
  if constexpr (__is_same(InT, float))
    aF = (const float*)A + (size_t)(rp * 128 + srow) * 256 + kq * 16;
  else
    aH = (const unsigned short*)A + (size_t)(rp * 128 + srow) * 256 + kq * 16;
  const unsigned short* bp = BT + (size_t)(cp * 128 + srow) * 256 + kq * 16;

  // wave compute mapping: 8 waves = 2 (row) x 4 (col); wave tile 64 x 32
  int wid = tid >> 6, lane = tid & 63, l15 = lane & 15, slot = lane >> 4;
  int wr = (wid >> 2) * 64;         // 0 / 64
  int wc = (wid & 3) * 32;          // 0,32,64,96

  f32x4 acc[4][2] = {};

  // prefetch registers (single set; loads for kt+1 issued right after staging kt)
  float4 af0, af1, af2, af3;        // fp32 A path (16 floats)
  u16x8 ah0, ah1;                   // bf16 A path
  u16x8 bh0, bh1;                   // B path

#define LOADK(kt) do { \
    if constexpr (__is_same(InT, float)) { \
      const float* ap = aF + (kt) * 64; \
      af0 = *(const float4*)ap;       af1 = *(const float4*)(ap + 4); \
      af2 = *(const float4*)(ap + 8); af3 = *(const float4*)(ap + 12); \
    } else { \
      const unsigned short* ap = aH + (kt) * 64; \
      ah0 = *(const u16x8*)ap; ah1 = *(const u16x8*)(ap + 8); \
    } \
    const unsigned short* bq = bp + (kt) * 64; \
    bh0 = *(const u16x8*)bq; bh1 = *(const u16x8*)(bq + 8); \
  } while (0)

  LOADK(0);

  for (int kt = 0; kt < 4; ++kt) {
    // ---- stage current tile into swizzled LDS ----
    u16x8 w0, w1;
    if constexpr (__is_same(InT, float)) {
      w0[0]=f2bf(af0.x); w0[1]=f2bf(af0.y); w0[2]=f2bf(af0.z); w0[3]=f2bf(af0.w);
      w0[4]=f2bf(af1.x); w0[5]=f2bf(af1.y); w0[6]=f2bf(af1.z); w0[7]=f2bf(af1.w);
      w1[0]=f2bf(af2.x); w1[1]=f2bf(af2.y); w1[2]=f2bf(af2.z); w1[3]=f2bf(af2.w);
      w1[4]=f2bf(af3.x); w1[5]=f2bf(af3.y); w1[6]=f2bf(af3.z); w1[7]=f2bf(af3.w);
    } else {
      w0 = ah0; w1 = ah1;
    }
    *(u16x8*)&As[srow * 64 + ((kq2    ) ^ sw) * 8] = w0;
    *(u16x8*)&As[srow * 64 + ((kq2 + 1) ^ sw) * 8] = w1;
    *(u16x8*)&Bs[srow * 64 + ((kq2    ) ^ sw) * 8] = bh0;
    *(u16x8*)&Bs[srow * 64 + ((kq2 + 1) ^ sw) * 8] = bh1;

    if (kt < 3) LOADK(kt + 1);      // issue next tile's loads; they fly across compute

    asm volatile("s_waitcnt lgkmcnt(0)" ::: "memory");   // own LDS writes visible
    __builtin_amdgcn_s_barrier();                        // raw: does NOT drain vmcnt

    // ---- compute: 2 kf x (6 ds_read_b128 + 8 MFMA) per wave ----
#pragma unroll
    for (int kf = 0; kf < 2; ++kf) {
      short8 afr[4], bfr[2];
#pragma unroll
      for (int mm = 0; mm < 4; ++mm) {
        int row = wr + mm * 16 + l15;
        afr[mm] = *(const short8*)&As[row * 64 + (((kf * 4 + slot)) ^ (row & 7)) * 8];
      }
#pragma unroll
      for (int nn = 0; nn < 2; ++nn) {
        int col = wc + nn * 16 + l15;
        bfr[nn] = *(const short8*)&Bs[col * 64 + (((kf * 4 + slot)) ^ (col & 7)) * 8];
      }
#pragma unroll
      for (int mm = 0; mm < 4; ++mm)
#pragma unroll
        for (int nn = 0; nn < 2; ++nn)
          acc[mm][nn] = __builtin_amdgcn_mfma_f32_16x16x32_bf16(afr[mm], bfr[nn], acc[mm][nn], 0, 0, 0);
    }
    __builtin_amdgcn_s_barrier();   // LDS safe to overwrite next iteration
  }
#undef LOADK

  // ---- epilogue: C/D layout col=lane&15, row=(lane>>4)*4+j ----
#pragma unroll
  for (int mm = 0; mm < 4; ++mm) {
#pragma unroll
    for (int nn = 0; nn < 2; ++nn) {
      int grow0 = rp * 128 + wr + mm * 16 + slot * 4;
      int gcol  = cp * 128 + wc + nn * 16 + l15;
#pragma unroll
      for (int j = 0; j < 4; ++j) {
        size_t o = (size_t)(grow0 + j) * ldc + gcol;
        if constexpr (__is_same(OutT, float)) C[o] = acc[mm][nn][j];
        else                                  C[o] = __float2bfloat16(acc[mm][nn][j]);
      }
    }
  }
}

// ---------------- masked cross-attention: one wave per cell, online softmax ---------------
__global__ __launch_bounds__(256) void attn_kernel(
    const float* __restrict__ lat,          // [1024][768]  q|k|v
    const __hip_bfloat16* __restrict__ kv,  // [m*n][512]   k|v
    const int* __restrict__ pts2,           // [MS][16]: w0=eff, w1..15 sorted pt indices
    __hip_bfloat16* __restrict__ attn_out, int n) {
  const float scale = 0.17677669529663687f;  // 1/sqrt(32)
  int wid = threadIdx.x >> 6;
  int lane = threadIdx.x & 63;
  int cellg = blockIdx.x * 4 + wid;
  int b = cellg >> 13;                 // S_=8192, cells per batch
  int c = cellg & (SP_ - 1);           // spatial index -> latent row
  int d0 = lane << 2;                  // 4 dims per lane

  const int* pp = pts2 + (size_t)cellg * P_;
  int4 h0 = *(const int4*)pp;          // eff, pt0, pt1, pt2 (broadcast load)
  int eff = h0.x;

  const float* latc = lat + c * 768 + d0;
  float4 q  = *(const float4*)latc;
  float4 kl = *(const float4*)(latc + 256);
  float4 vl = *(const float4*)(latc + 512);

  // grid-token logit -> init online-softmax state
  float part = q.x*kl.x + q.y*kl.y + q.z*kl.z + q.w*kl.w;
  part += __shfl_xor(part, 1);
  part += __shfl_xor(part, 2);
  part += __shfl_xor(part, 4);         // head-local (8 lanes = 32 dims)
  float mx = part * scale;
  float ssum = 1.f;
  float4 acc = vl;

  const unsigned short* kvp = (const unsigned short*)kv;
  size_t bbase = (size_t)b * n;

  int pt[4]; pt[0] = h0.y; pt[1] = h0.z; pt[2] = h0.w; pt[3] = 0;
  int done = 0, cap = 3;
  while (done < eff) {
    int np = eff - done; if (np > cap) np = cap;
    ushort4 kr[4], vr[4];
#pragma unroll
    for (int i = 0; i < 4; ++i) if (i < np) {
      size_t row = (bbase + (size_t)pt[i]) * 512;
      kr[i] = *(const ushort4*)(kvp + row + d0);
      vr[i] = *(const ushort4*)(kvp + row + 256 + d0);
    }
#pragma unroll
    for (int i = 0; i < 4; ++i) if (i < np) {
      float p = q.x*bf2f(kr[i].x) + q.y*bf2f(kr[i].y) + q.z*bf2f(kr[i].z) + q.w*bf2f(kr[i].w);
      p += __shfl_xor(p, 1);
      p += __shfl_xor(p, 2);
      p += __shfl_xor(p, 4);
      p *= scale;
      float m2 = fmaxf(mx, p);
      float corr = __expf(mx - m2);
      float e = __expf(p - m2);
      ssum = ssum * corr + e;
      acc.x = acc.x * corr + e * bf2f(vr[i].x);
      acc.y = acc.y * corr + e * bf2f(vr[i].y);
      acc.z = acc.z * corr + e * bf2f(vr[i].z);
      acc.w = acc.w * corr + e * bf2f(vr[i].w);
      mx = m2;
    }
    done += np;
    cap = 4;
    if (done < eff) {
      int4 h = *(const int4*)(pp + 1 + done);   // done in {3,7,11} -> aligned
      pt[0] = h.x; pt[1] = h.y; pt[2] = h.z; pt[3] = h.w;
    }
  }
  float inv = 1.f / ssum;
  ushort4 o;
  o.x = f2bf(acc.x * inv); o.y = f2bf(acc.y * inv);
  o.z = f2bf(acc.z * inv); o.w = f2bf(acc.w * inv);
  *(ushort4*)((unsigned short*)attn_out + (size_t)cellg * E_ + d0) = o;
}

// -------------------------------------------------------------------------------------------
extern "C" void kernel_launch(void* const* d_in, const int* in_sizes, int n_in,
                              void* d_out, int out_size, void* d_ws, size_t ws_size,
                              hipStream_t stream) {
  const float* x       = (const float*)d_in[0];
  const float* z       = (const float*)d_in[1];
  const float* tg      = (const float*)d_in[2];
  const float* latents = (const float*)d_in[3];
  const float* grid    = (const float*)d_in[4];
  const float* Wq      = (const float*)d_in[5];
  const float* Wk      = (const float*)d_in[6];
  const float* Wv      = (const float*)d_in[7];
  const float* Wo      = (const float*)d_in[8];

  int m = in_sizes[2] / T_;              // 4
  int n = in_sizes[1] / (m * E_);        // 16384
  int MS = m * S_;                       // 32768
  float* out = (float*)d_out;

  // ---- workspace carve (256B aligned) ----
  char* w = (char*)d_ws;
  auto alloc = [&](size_t bytes) { char* p = w; w += (bytes + 255) & ~(size_t)255; return p; };
  float* stats      = (float*)alloc((size_t)m * 8 * 4);
  int*   counts     = (int*)  alloc((size_t)MS * 4);
  int*   cell_raw   = (int*)  alloc((size_t)MS * P_ * 4);
  int*   pts2       = (int*)  alloc((size_t)MS * P_ * 4);
  unsigned short* wT = (unsigned short*)alloc((size_t)1024 * 256 * 2);
  float* lat        = (float*)alloc((size_t)SP_ * 768 * 4);
  __hip_bfloat16* kv       = (__hip_bfloat16*)alloc((size_t)m * n * 512 * 2);
  __hip_bfloat16* attn_out = (__hip_bfloat16*)alloc((size_t)MS * E_ * 2);

  hipMemsetAsync(counts, 0, (size_t)MS * 4, stream);
  stats_kernel<<<1, 64, 0, stream>>>(tg, grid, stats, m);

  int tot_xg = m * T_ * SP_;             // 32768 grid sites
  xgrid_kernel<<<(tot_xg + 255)/256, 256, 0, stream>>>(tg, grid, out, tot_xg);

  assign_kernel<<<(m*n + 255)/256, 256, 0, stream>>>(x, stats, counts, cell_raw, m, n);
  finalize_kernel<<<(MS + 255)/256, 256, 0, stream>>>(counts, cell_raw, pts2, MS);

  // weights: transpose + convert to bf16  [Wq|Wk|Wv|Wo]^T
  wtrans_kernel<<<64, 256, 0, stream>>>(Wq, Wk, Wv, Wo, wT);

  // latent projections fused: lat[1024,768] = latents @ [Wq|Wk|Wv]   (8 rp x 6 cp = 48)
  gemm_ktile<float, float><<<48, 512, 0, stream>>>(latents, wT, lat, SP_, 6, 768);

  // point projections fused: kv[m*n,512] = z @ [Wk|Wv]   (512 rp x 4 cp = 2048)
  gemm_ktile<float, __hip_bfloat16><<<2048, 512, 0, stream>>>(
      z, wT + (size_t)256*256, (__hip_bfloat16*)kv, m*n, 4, 512);

  // attention: one wave per cell
  attn_kernel<<<MS/4, 256, 0, stream>>>(lat, kv, pts2, attn_out, n);

  // output projection -> z_grid   (256 rp x 2 cp = 512)
  gemm_ktile<__hip_bfloat16, float><<<512, 512, 0, stream>>>(
      attn_out, wT + (size_t)768*256, out + (size_t)tot_xg * 3, MS, 2, 256);
}